// Round 1
// baseline (398.739 us; speedup 1.0000x reference)
//
#include <hip/hip_runtime.h>
#include <hip/hip_bf16.h>
#include <cstdint>
#include <cstddef>

typedef __bf16 bf16;
typedef __attribute__((ext_vector_type(8))) __bf16 bf16x8;
typedef __attribute__((ext_vector_type(4))) __bf16 bf16x4;
typedef __attribute__((ext_vector_type(4))) float f32x4;

#define B_ 2
#define S_ 2048
#define D_ 1024
#define H_ 16
#define DK_ 64
#define NROWS (B_*S_)   // 4096
#define NBIAS 4095      // rel in [-2047,2047]

__device__ __forceinline__ void async16(void* lds, const void* g) {
  __builtin_amdgcn_global_load_lds(
      (const __attribute__((address_space(1))) void*)g,
      (__attribute__((address_space(3))) void*)lds, 16, 0, 0);
}

__device__ __forceinline__ f32x4 mfma16(bf16x8 a, bf16x8 b, f32x4 c) {
  return __builtin_amdgcn_mfma_f32_16x16x32_bf16(a, b, c, 0, 0, 0);
}

// ---------------------------------------------------------------- f32 -> bf16
__global__ void cvt_kernel(const float* __restrict__ in, bf16* __restrict__ out, int n4) {
  int i = blockIdx.x * blockDim.x + threadIdx.x;
  if (i >= n4) return;
  float4 v = ((const float4*)in)[i];
  bf16x4 o;
  o[0] = (bf16)v.x; o[1] = (bf16)v.y; o[2] = (bf16)v.z; o[3] = (bf16)v.w;
  ((bf16x4*)out)[i] = o;
}

// ------------------------------------------------- T5 relative bias table
// tab[h][idx], idx = (k - q) + 2047
__global__ void bias_kernel(const float* __restrict__ rel_emb, float* __restrict__ tab) {
  int idx = blockIdx.x * 256 + threadIdx.x;
  if (idx >= H_ * NBIAS) return;
  int h = idx / NBIAS;
  int p = idx - h * NBIAS;
  int rel = p - 2047;          // k - q  (mem - ctx)
  int n = -rel;                // per reference: n = -relative_position
  int ret = 0;
  if (n < 0) { ret = 16; n = -n; }
  int bucket;
  if (n < 8) {
    bucket = ret + n;
  } else {
    double v = log((double)n / 8.0) / log(16.0) * 8.0;
    int vi = 8 + (int)v;
    if (vi > 15) vi = 15;
    bucket = ret + vi;
  }
  tab[idx] = rel_emb[bucket * H_ + h];
}

// ---------------------------------------------------------------- GEMM (bt)
// C[M][N] = alpha * A[M][K] @ B[N][K]^T ; A,B bf16 row-major; C f32 or bf16
// tile 64(M) x 128(N) x 64(K); 256 threads = 4 waves, wave grid 2x2,
// each wave 32x64 (2x4 frags of 16x16).
template<int OUT_BF16>
__global__ __launch_bounds__(256, 2)
void gemm_bt(const bf16* __restrict__ A, const bf16* __restrict__ Bw,
             void* __restrict__ C, int M, int N, int K, float alpha) {
  __shared__ bf16 As[64 * 64];
  __shared__ bf16 Bs[128 * 64];
  const int tid = threadIdx.x;
  const int lane = tid & 63;
  const int w = tid >> 6;
  const int wr = w >> 1, wc = w & 1;
  const int l15 = lane & 15, lhi = lane >> 4;
  const int m0 = blockIdx.y * 64, n0 = blockIdx.x * 128;

  f32x4 acc[2][4] = {};

  const int urow = tid >> 3;                 // 0..31
  const int uswz = (tid & 7) ^ (urow & 7);   // pre-swizzled global 16B unit
  const bf16* ga = A  + (size_t)(m0 + urow) * K + uswz * 8;
  const bf16* gb = Bw + (size_t)(n0 + urow) * K + uswz * 8;

  for (int kt = 0; kt < K; kt += 64) {
    async16(As + tid * 8,        ga + kt);
    async16(As + tid * 8 + 2048, ga + kt + (size_t)32 * K);
    async16(Bs + tid * 8,        gb + kt);
    async16(Bs + tid * 8 + 2048, gb + kt + (size_t)32 * K);
    async16(Bs + tid * 8 + 4096, gb + kt + (size_t)64 * K);
    async16(Bs + tid * 8 + 6144, gb + kt + (size_t)96 * K);
    __syncthreads();

#pragma unroll
    for (int kc = 0; kc < 2; ++kc) {
      bf16x8 af[2], bfr[4];
#pragma unroll
      for (int m = 0; m < 2; ++m) {
        int row = wr * 32 + m * 16 + l15;
        int off = (row * 64 + kc * 32 + lhi * 8) ^ ((row & 7) << 3);
        af[m] = *(const bf16x8*)&As[off];
      }
#pragma unroll
      for (int n = 0; n < 4; ++n) {
        int row = wc * 64 + n * 16 + l15;
        int off = (row * 64 + kc * 32 + lhi * 8) ^ ((row & 7) << 3);
        bfr[n] = *(const bf16x8*)&Bs[off];
      }
#pragma unroll
      for (int m = 0; m < 2; ++m)
#pragma unroll
        for (int n = 0; n < 4; ++n)
          acc[m][n] = mfma16(af[m], bfr[n], acc[m][n]);
    }
    __syncthreads();
  }

#pragma unroll
  for (int m = 0; m < 2; ++m)
#pragma unroll
    for (int n = 0; n < 4; ++n)
#pragma unroll
      for (int r = 0; r < 4; ++r) {
        int row = m0 + wr * 32 + m * 16 + lhi * 4 + r;
        int col = n0 + wc * 64 + n * 16 + l15;
        float v = acc[m][n][r] * alpha;
        if (OUT_BF16) ((bf16*)C)[(size_t)row * N + col] = (bf16)v;
        else          ((float*)C)[(size_t)row * N + col] = v;
      }
}

// ---------------------------------------------------------------- attention
// grid: (S/128 q-tiles, B*H). 256 threads = 4 waves, wave w owns q rows
// [w*32, w*32+32). Flash loop over 128-wide K/V tiles.
__global__ __launch_bounds__(256, 2)
void attn_fwd(const bf16* __restrict__ Qg, const bf16* __restrict__ Kgb,
              const bf16* __restrict__ Vgb, const float* __restrict__ biasTab,
              bf16* __restrict__ Og) {
  __shared__ bf16 Ks[128 * 64];     // [kpos][d]   (swizzled via global src)
  __shared__ bf16 Vt[64 * 128];     // [d][kpos]   (XOR-swizzled)
  __shared__ bf16 Ps[128 * 128];    // [q][kpos]   (XOR-swizzled)
  __shared__ float bias_s[4096];
  const int tid = threadIdx.x;
  const int lane = tid & 63, w = tid >> 6;
  const int l15 = lane & 15, lhi = lane >> 4;
  const int bh = blockIdx.y, b = bh >> 4, h = bh & 15;
  const int q0 = blockIdx.x * 128;

  for (int i = tid; i < NBIAS; i += 256) bias_s[i] = biasTab[h * NBIAS + i];

  // Q fragments (Q already scaled by 1/8): rows q0+w*32 .. +32
  bf16x8 qa[2][2];
  {
    const bf16* Qbase = Qg + ((size_t)(b * S_ + q0 + w * 32)) * D_ + h * DK_;
#pragma unroll
    for (int qf = 0; qf < 2; ++qf)
#pragma unroll
      for (int c = 0; c < 2; ++c)
        qa[qf][c] = *(const bf16x8*)(Qbase + (size_t)(qf * 16 + l15) * D_ + c * 32 + lhi * 8);
  }

  float mrow[2][4], lrow[2][4];
#pragma unroll
  for (int qf = 0; qf < 2; ++qf)
#pragma unroll
    for (int r = 0; r < 4; ++r) { mrow[qf][r] = -1e30f; lrow[qf][r] = 0.f; }
  f32x4 oacc[2][4] = {};

  const bf16* Kg = Kgb + (size_t)(b * S_) * D_ + h * DK_;
  const bf16* Vg = Vgb + (size_t)(b * S_) * D_ + h * DK_;
  const int urow = tid >> 3;
  const int uswz = (tid & 7) ^ (urow & 7);

  __syncthreads();  // bias_s ready

  for (int kt = 0; kt < S_; kt += 128) {
    // stage K tile (async, linear LDS; source pre-swizzled)
    {
      const bf16* gk = Kg + (size_t)(kt + urow) * D_ + uswz * 8;
      async16(Ks + tid * 8,        gk);
      async16(Ks + tid * 8 + 2048, gk + (size_t)32 * D_);
      async16(Ks + tid * 8 + 4096, gk + (size_t)64 * D_);
      async16(Ks + tid * 8 + 6144, gk + (size_t)96 * D_);
    }
    // stage V transposed (reg path, XOR swizzle on row&7)
    {
      const int c8 = tid & 7;
#pragma unroll
      for (int it = 0; it < 4; ++it) {
        int r = urow + it * 32;
        bf16x8 v = *(const bf16x8*)(Vg + (size_t)(kt + r) * D_ + c8 * 8);
#pragma unroll
        for (int j = 0; j < 8; ++j) {
          int row = c8 * 8 + j;                      // d index
          int byteoff = (row * 256 + r * 2) ^ ((row & 7) << 4);
          *(bf16*)((char*)Vt + byteoff) = v[j];
        }
      }
    }
    __syncthreads();

    // S = Q @ K^T  (per wave: 32 q-rows x 128 k-cols)
    f32x4 sacc[2][8] = {};
#pragma unroll
    for (int kf = 0; kf < 8; ++kf) {
#pragma unroll
      for (int c = 0; c < 2; ++c) {
        int row = kf * 16 + l15;
        int off = (row * 64 + c * 32 + lhi * 8) ^ ((row & 7) << 3);
        bf16x8 kb = *(const bf16x8*)&Ks[off];
        sacc[0][kf] = mfma16(qa[0][c], kb, sacc[0][kf]);
        sacc[1][kf] = mfma16(qa[1][c], kb, sacc[1][kf]);
      }
    }

    // bias + online softmax (f32)
#pragma unroll
    for (int qf = 0; qf < 2; ++qf) {
#pragma unroll
      for (int r = 0; r < 4; ++r) {
        const int qrow = q0 + w * 32 + qf * 16 + lhi * 4 + r;
        const int bbase = kt - qrow + 2047 + l15;
        float mx = -1e30f;
#pragma unroll
        for (int kf = 0; kf < 8; ++kf) {
          float s = sacc[qf][kf][r] + bias_s[bbase + kf * 16];
          sacc[qf][kf][r] = s;
          mx = fmaxf(mx, s);
        }
#pragma unroll
        for (int d = 1; d < 16; d <<= 1) mx = fmaxf(mx, __shfl_xor(mx, d));
        float mold = mrow[qf][r];
        float mnew = fmaxf(mold, mx);
        float scl = __expf(mold - mnew);
        float rsum = 0.f;
#pragma unroll
        for (int kf = 0; kf < 8; ++kf) {
          float p = __expf(sacc[qf][kf][r] - mnew);
          sacc[qf][kf][r] = p;
          rsum += p;
        }
#pragma unroll
        for (int d = 1; d < 16; d <<= 1) rsum += __shfl_xor(rsum, d);
        mrow[qf][r] = mnew;
        lrow[qf][r] = lrow[qf][r] * scl + rsum;
#pragma unroll
        for (int df = 0; df < 4; ++df) oacc[qf][df][r] *= scl;
      }
    }

    // write P quadrant to LDS (bf16, swizzled) — wave-local
#pragma unroll
    for (int qf = 0; qf < 2; ++qf)
#pragma unroll
      for (int kf = 0; kf < 8; ++kf)
#pragma unroll
        for (int r = 0; r < 4; ++r) {
          int prow = w * 32 + qf * 16 + lhi * 4 + r;
          int byteoff = ((prow * 128 + kf * 16 + l15) * 2) ^ ((prow & 7) << 4);
          *(bf16*)((char*)Ps + byteoff) = (bf16)sacc[qf][kf][r];
        }

    // O += P @ V
#pragma unroll
    for (int kc = 0; kc < 4; ++kc) {
      bf16x8 pa[2], vb[4];
#pragma unroll
      for (int qf = 0; qf < 2; ++qf) {
        int prow = w * 32 + qf * 16 + l15;
        int byteoff = ((prow * 128 + kc * 32 + lhi * 8) * 2) ^ ((prow & 7) << 4);
        pa[qf] = *(const bf16x8*)((const char*)Ps + byteoff);
      }
#pragma unroll
      for (int df = 0; df < 4; ++df) {
        int row = df * 16 + l15;
        int byteoff = ((row * 128 + kc * 32 + lhi * 8) * 2) ^ ((row & 7) << 4);
        vb[df] = *(const bf16x8*)((const char*)Vt + byteoff);
      }
#pragma unroll
      for (int qf = 0; qf < 2; ++qf)
#pragma unroll
        for (int df = 0; df < 4; ++df)
          oacc[qf][df] = mfma16(pa[qf], vb[df], oacc[qf][df]);
    }
    __syncthreads();
  }

  // epilogue: normalize + store bf16
#pragma unroll
  for (int qf = 0; qf < 2; ++qf)
#pragma unroll
    for (int df = 0; df < 4; ++df)
#pragma unroll
      for (int r = 0; r < 4; ++r) {
        int row = b * S_ + q0 + w * 32 + qf * 16 + lhi * 4 + r;
        int col = h * DK_ + df * 16 + l15;
        Og[(size_t)row * D_ + col] = (bf16)(oacc[qf][df][r] / lrow[qf][r]);
      }
}

// ---------------------------------------------------------------- launch
extern "C" void kernel_launch(void* const* d_in, const int* in_sizes, int n_in,
                              void* d_out, int out_size, void* d_ws, size_t ws_size,
                              hipStream_t stream) {
  const float* X   = (const float*)d_in[0];
  const float* Wq  = (const float*)d_in[1];
  const float* Wk  = (const float*)d_in[2];
  const float* Wv  = (const float*)d_in[3];
  const float* Wo  = (const float*)d_in[4];
  const float* rel = (const float*)d_in[5];
  float* out = (float*)d_out;
  char* ws = (char*)d_ws;
  const size_t MB = 1u << 20;
  bf16* Xb  = (bf16*)(ws + 0 * MB);    // 8 MB
  bf16* Wqb = (bf16*)(ws + 8 * MB);    // 2 MB
  bf16* Wkb = (bf16*)(ws + 10 * MB);
  bf16* Wvb = (bf16*)(ws + 12 * MB);
  bf16* Wob = (bf16*)(ws + 14 * MB);
  bf16* Qb  = (bf16*)(ws + 16 * MB);   // 8 MB
  bf16* Kb  = (bf16*)(ws + 24 * MB);
  bf16* Vb  = (bf16*)(ws + 32 * MB);
  bf16* Ob  = (bf16*)(ws + 40 * MB);
  float* biasTab = (float*)(ws + 48 * MB);  // 16*4095*4 B

  cvt_kernel<<<4096, 256, 0, stream>>>(X,  Xb,  NROWS * D_ / 4);
  cvt_kernel<<<1024, 256, 0, stream>>>(Wq, Wqb, D_ * D_ / 4);
  cvt_kernel<<<1024, 256, 0, stream>>>(Wk, Wkb, D_ * D_ / 4);
  cvt_kernel<<<1024, 256, 0, stream>>>(Wv, Wvb, D_ * D_ / 4);
  cvt_kernel<<<1024, 256, 0, stream>>>(Wo, Wob, D_ * D_ / 4);
  bias_kernel<<<256, 256, 0, stream>>>(rel, biasTab);

  dim3 ggrid(D_ / 128, NROWS / 64);  // (8, 64)
  gemm_bt<1><<<ggrid, 256, 0, stream>>>(Xb, Wqb, Qb, NROWS, D_, D_, 0.125f); // fold 1/sqrt(dk)
  gemm_bt<1><<<ggrid, 256, 0, stream>>>(Xb, Wkb, Kb, NROWS, D_, D_, 1.0f);
  gemm_bt<1><<<ggrid, 256, 0, stream>>>(Xb, Wvb, Vb, NROWS, D_, D_, 1.0f);

  attn_fwd<<<dim3(S_ / 128, B_ * H_), 256, 0, stream>>>(Qb, Kb, Vb, biasTab, Ob);

  gemm_bt<0><<<ggrid, 256, 0, stream>>>(Ob, Wob, out, NROWS, D_, D_, 1.0f);
}

// Round 2
// 143.352 us; speedup vs baseline: 2.7815x; 2.7815x over previous
//
#include <hip/hip_runtime.h>
#include <hip/hip_bf16.h>
#include <cstdint>
#include <cstddef>

typedef __bf16 bf16;
typedef __attribute__((ext_vector_type(8))) __bf16 bf16x8;
typedef __attribute__((ext_vector_type(4))) __bf16 bf16x4;
typedef __attribute__((ext_vector_type(4))) float f32x4;

#define B_ 2
#define S_ 2048
#define D_ 1024
#define H_ 16
#define DK_ 64
#define NROWS (B_*S_)   // 4096
#define NBIAS 4095      // rel in [-2047,2047]
#define LDQ 3072        // fused QKV row stride

__device__ __forceinline__ void async16(void* lds, const void* g) {
  __builtin_amdgcn_global_load_lds(
      (const __attribute__((address_space(1))) void*)g,
      (__attribute__((address_space(3))) void*)lds, 16, 0, 0);
}

__device__ __forceinline__ f32x4 mfma16(bf16x8 a, bf16x8 b, f32x4 c) {
  return __builtin_amdgcn_mfma_f32_16x16x32_bf16(a, b, c, 0, 0, 0);
}

// ---------------------------------------------------------------- f32 -> bf16
__global__ void cvt_kernel(const float* __restrict__ in, bf16* __restrict__ out, int n4) {
  int i = blockIdx.x * blockDim.x + threadIdx.x;
  if (i >= n4) return;
  float4 v = ((const float4*)in)[i];
  bf16x4 o;
  o[0] = (bf16)v.x; o[1] = (bf16)v.y; o[2] = (bf16)v.z; o[3] = (bf16)v.w;
  ((bf16x4*)out)[i] = o;
}

// ------------------------------------------------- T5 relative bias table
// tab[h][idx], idx = (k - q) + 2047
__global__ void bias_kernel(const float* __restrict__ rel_emb, float* __restrict__ tab) {
  int idx = blockIdx.x * 256 + threadIdx.x;
  if (idx >= H_ * NBIAS) return;
  int h = idx / NBIAS;
  int p = idx - h * NBIAS;
  int rel = p - 2047;          // k - q  (mem - ctx)
  int n = -rel;                // per reference: n = -relative_position
  int ret = 0;
  if (n < 0) { ret = 16; n = -n; }
  int bucket;
  if (n < 8) {
    bucket = ret + n;
  } else {
    double v = log((double)n / 8.0) / log(16.0) * 8.0;
    int vi = 8 + (int)v;
    if (vi > 15) vi = 15;
    bucket = ret + vi;
  }
  tab[idx] = rel_emb[bucket * H_ + h];
}

// ---------------------------------------------------------------- GEMM (bt)
// C[M][N] = alpha * A[M][K] @ B[N][K]^T ; alpha = (n0 < colThr) ? a0 : a1
// tile 64(M) x 128(N) x 64(K); 256 threads = 4 waves (2x2), wave 32x64.
template<int OUT_BF16>
__global__ __launch_bounds__(256, 2)
void gemm_bt(const bf16* __restrict__ A, const bf16* __restrict__ Bw,
             void* __restrict__ C, int M, int N, int K,
             int colThr, float a0, float a1) {
  __shared__ bf16 As[64 * 64];
  __shared__ bf16 Bs[128 * 64];
  const int tid = threadIdx.x;
  const int lane = tid & 63;
  const int w = tid >> 6;
  const int wr = w >> 1, wc = w & 1;
  const int l15 = lane & 15, lhi = lane >> 4;
  const int m0 = blockIdx.y * 64, n0 = blockIdx.x * 128;
  const float alpha = (n0 < colThr) ? a0 : a1;

  f32x4 acc[2][4] = {};

  const int urow = tid >> 3;                 // 0..31
  const int uswz = (tid & 7) ^ (urow & 7);   // pre-swizzled global 16B unit
  const bf16* ga = A  + (size_t)(m0 + urow) * K + uswz * 8;
  const bf16* gb = Bw + (size_t)(n0 + urow) * K + uswz * 8;

  for (int kt = 0; kt < K; kt += 64) {
    async16(As + tid * 8,        ga + kt);
    async16(As + tid * 8 + 2048, ga + kt + (size_t)32 * K);
    async16(Bs + tid * 8,        gb + kt);
    async16(Bs + tid * 8 + 2048, gb + kt + (size_t)32 * K);
    async16(Bs + tid * 8 + 4096, gb + kt + (size_t)64 * K);
    async16(Bs + tid * 8 + 6144, gb + kt + (size_t)96 * K);
    __syncthreads();

#pragma unroll
    for (int kc = 0; kc < 2; ++kc) {
      bf16x8 af[2], bfr[4];
#pragma unroll
      for (int m = 0; m < 2; ++m) {
        int row = wr * 32 + m * 16 + l15;
        int off = (row * 64 + kc * 32 + lhi * 8) ^ ((row & 7) << 3);
        af[m] = *(const bf16x8*)&As[off];
      }
#pragma unroll
      for (int n = 0; n < 4; ++n) {
        int row = wc * 64 + n * 16 + l15;
        int off = (row * 64 + kc * 32 + lhi * 8) ^ ((row & 7) << 3);
        bfr[n] = *(const bf16x8*)&Bs[off];
      }
#pragma unroll
      for (int m = 0; m < 2; ++m)
#pragma unroll
        for (int n = 0; n < 4; ++n)
          acc[m][n] = mfma16(af[m], bfr[n], acc[m][n]);
    }
    __syncthreads();
  }

#pragma unroll
  for (int m = 0; m < 2; ++m)
#pragma unroll
    for (int n = 0; n < 4; ++n)
#pragma unroll
      for (int r = 0; r < 4; ++r) {
        int row = m0 + wr * 32 + m * 16 + lhi * 4 + r;
        int col = n0 + wc * 64 + n * 16 + l15;
        float v = acc[m][n][r] * alpha;
        if (OUT_BF16) ((bf16*)C)[(size_t)row * N + col] = (bf16)v;
        else          ((float*)C)[(size_t)row * N + col] = v;
      }
}

// ------------------------------------------- V transpose: QKV cols 2048.. -> VT
// VT[b*1024 + d][s] = QKV[b*2048 + s][2048 + d].  8x8 micro-tile per thread.
__global__ __launch_bounds__(256)
void transpose_v(const bf16* __restrict__ Q, bf16* __restrict__ VT) {
  const int t = threadIdx.x;
  const int ms = t >> 4, md = t & 15;
  const int s0 = blockIdx.x * 128, d0 = blockIdx.y * 128, b = blockIdx.z;
  bf16x8 in[8];
  const bf16* src = Q + (size_t)(b * 2048 + s0 + ms * 8) * LDQ + 2048 + d0 + md * 8;
#pragma unroll
  for (int i = 0; i < 8; ++i) in[i] = *(const bf16x8*)(src + (size_t)i * LDQ);
  bf16* dst = VT + (size_t)(b * 1024 + d0 + md * 8) * 2048 + s0 + ms * 8;
#pragma unroll
  for (int j = 0; j < 8; ++j) {
    bf16x8 o;
#pragma unroll
    for (int i = 0; i < 8; ++i) o[i] = in[i][j];
    *(bf16x8*)(dst + (size_t)j * 2048) = o;
  }
}

// ---------------------------------------------------------------- attention
// 1-D grid of 512: wg = qt*32 + bh  (bh fastest -> same head's q-tiles share XCD L2)
// 256 threads = 4 waves; wave w owns q rows [q0+w*32, +32).
// Swapped QK^T: st = mfma(K_frag, Q_frag) -> lane holds q=l15, k=kf*16+lhi*4+r.
__global__ __launch_bounds__(256, 2)
void attn_fwd(const bf16* __restrict__ QKV, const bf16* __restrict__ VTg_,
              const float* __restrict__ biasTab, bf16* __restrict__ Og) {
  __shared__ bf16 Ks[128 * 64];     // [kpos][d]  swizzled via pre-swizzled source
  __shared__ bf16 VTs[64 * 128];    // [d][kpos]  swizzled via pre-swizzled source
  __shared__ bf16 Ps[128 * 128];    // [q][k]     XOR-swizzled
  __shared__ float bias_s[2176];    // window: idx = k - q + q0 + 127 - ... see below
  const int tid = threadIdx.x;
  const int lane = tid & 63, w = tid >> 6;
  const int l15 = lane & 15, lhi = lane >> 4;
  const int wg = blockIdx.x;
  const int bh = wg & 31, qt = wg >> 5;
  const int b = bh >> 4, h = bh & 15;
  const int q0 = qt * 128;

  // bias window covers k-q+2047 in [1920-q0, 4094-q0]
  for (int i = tid; i < 2176; i += 256)
    bias_s[i] = biasTab[h * NBIAS + (1920 - q0) + i];

  // Q fragments (already scaled 0.125 in QKV gemm): B-operand of swapped QK^T
  bf16x8 qa[2][2];
  {
    const bf16* Qbase = QKV + (size_t)(b * S_ + q0 + w * 32) * LDQ + h * DK_;
#pragma unroll
    for (int qf = 0; qf < 2; ++qf)
#pragma unroll
      for (int c = 0; c < 2; ++c)
        qa[qf][c] = *(const bf16x8*)(Qbase + (size_t)(qf * 16 + l15) * LDQ + c * 32 + lhi * 8);
  }

  float mrow[2] = {-1e30f, -1e30f}, lrow[2] = {0.f, 0.f};
  f32x4 oacc[2][4] = {};

  const bf16* Kg  = QKV  + (size_t)(b * S_) * LDQ + 1024 + h * DK_;
  const bf16* VTg = VTg_ + (size_t)(b * 1024 + h * DK_) * 2048;
  const int urow = tid >> 3;
  const int uswz = (tid & 7) ^ (urow & 7);
  const int vrow = tid >> 4;
  const int vswz = (tid & 15) ^ (vrow & 7);

  __syncthreads();  // bias_s ready

  for (int kt = 0; kt < S_; kt += 128) {
    // stage K [128 kpos][64 d] (4 chunks of 32 rows)
    {
      const bf16* gk = Kg + (size_t)(kt + urow) * LDQ + uswz * 8;
      async16(Ks + tid * 8,        gk);
      async16(Ks + tid * 8 + 2048, gk + (size_t)32 * LDQ);
      async16(Ks + tid * 8 + 4096, gk + (size_t)64 * LDQ);
      async16(Ks + tid * 8 + 6144, gk + (size_t)96 * LDQ);
    }
    // stage V^T [64 d][128 kpos] (4 chunks of 16 rows)
    {
      const bf16* gv = VTg + (size_t)vrow * 2048 + kt + vswz * 8;
      async16(VTs + tid * 8,        gv);
      async16(VTs + tid * 8 + 2048, gv + (size_t)16 * 2048);
      async16(VTs + tid * 8 + 4096, gv + (size_t)32 * 2048);
      async16(VTs + tid * 8 + 6144, gv + (size_t)48 * 2048);
    }
    __syncthreads();

    // swapped S^T = K @ Q^T : st[qf][kf], lane: q=l15, k=kf*16+lhi*4+r
    f32x4 st[2][8] = {};
#pragma unroll
    for (int kf = 0; kf < 8; ++kf) {
#pragma unroll
      for (int c = 0; c < 2; ++c) {
        int krow = kf * 16 + l15;
        int off = (krow * 64 + c * 32 + lhi * 8) ^ ((krow & 7) << 3);
        bf16x8 kb = *(const bf16x8*)&Ks[off];
        st[0][kf] = mfma16(kb, qa[0][c], st[0][kf]);
        st[1][kf] = mfma16(kb, qa[1][c], st[1][kf]);
      }
    }

    // shared bias slots: qf=0 uses br[kf+1], qf=1 uses br[kf]
    const int bb0 = kt + lhi * 4 - (w * 32 + l15) + 127;  // >= 0
    float br[9][4];
#pragma unroll
    for (int s2 = 0; s2 < 9; ++s2)
#pragma unroll
      for (int r = 0; r < 4; ++r)
        br[s2][r] = bias_s[bb0 + (s2 - 1) * 16 + r];

#pragma unroll
    for (int qf = 0; qf < 2; ++qf) {
      float mx = -1e30f;
#pragma unroll
      for (int kf = 0; kf < 8; ++kf)
#pragma unroll
        for (int r = 0; r < 4; ++r) {
          float s = st[qf][kf][r] + br[kf + 1 - qf][r];
          st[qf][kf][r] = s;
          mx = fmaxf(mx, s);
        }
      mx = fmaxf(mx, __shfl_xor(mx, 16));
      mx = fmaxf(mx, __shfl_xor(mx, 32));
      float mold = mrow[qf];
      float mnew = fmaxf(mold, mx);
      float scl = __expf(mold - mnew);
      float rs = 0.f;
#pragma unroll
      for (int kf = 0; kf < 8; ++kf)
#pragma unroll
        for (int r = 0; r < 4; ++r) {
          float p = __expf(st[qf][kf][r] - mnew);
          st[qf][kf][r] = p;
          rs += p;
        }
      rs += __shfl_xor(rs, 16);
      rs += __shfl_xor(rs, 32);
      mrow[qf] = mnew;
      lrow[qf] = lrow[qf] * scl + rs;
      // rescale O rows (oacc row = lhi*4+r; scl lives on lane row l15)
#pragma unroll
      for (int r = 0; r < 4; ++r) {
        float sr = __shfl(scl, lhi * 4 + r);
#pragma unroll
        for (int df = 0; df < 4; ++df) oacc[qf][df][r] *= sr;
      }
      // P -> LDS, vectorized b64 (4 consecutive k per lane)
#pragma unroll
      for (int kf = 0; kf < 8; ++kf) {
        bf16x4 pk;
#pragma unroll
        for (int r = 0; r < 4; ++r) pk[r] = (bf16)st[qf][kf][r];
        int prow = w * 32 + qf * 16 + l15;
        int byteoff = ((prow * 128 + kf * 16 + lhi * 4) * 2) ^ ((l15 & 7) << 4);
        *(bf16x4*)((char*)Ps + byteoff) = pk;
      }
    }

    // O += P @ V  (A=P rows q=l15; B=V via VTs rows d)
#pragma unroll
    for (int kc = 0; kc < 4; ++kc) {
      bf16x8 pa[2], vb[4];
#pragma unroll
      for (int qf = 0; qf < 2; ++qf) {
        int prow = w * 32 + qf * 16 + l15;
        int byteoff = ((prow * 128 + kc * 32 + lhi * 8) * 2) ^ ((l15 & 7) << 4);
        pa[qf] = *(const bf16x8*)((const char*)Ps + byteoff);
      }
#pragma unroll
      for (int df = 0; df < 4; ++df) {
        int drow = df * 16 + l15;
        int byteoff = ((drow * 128 + kc * 32 + lhi * 8) * 2) ^ ((l15 & 7) << 4);
        vb[df] = *(const bf16x8*)((const char*)VTs + byteoff);
      }
#pragma unroll
      for (int qf = 0; qf < 2; ++qf)
#pragma unroll
        for (int df = 0; df < 4; ++df)
          oacc[qf][df] = mfma16(pa[qf], vb[df], oacc[qf][df]);
    }
    __syncthreads();
  }

  // epilogue: normalize + store bf16 (O row = lhi*4+r; l lives on lane row l15)
#pragma unroll
  for (int qf = 0; qf < 2; ++qf) {
#pragma unroll
    for (int r = 0; r < 4; ++r) {
      float lr = __shfl(lrow[qf], lhi * 4 + r);
      float inv = 1.0f / lr;
#pragma unroll
      for (int df = 0; df < 4; ++df) {
        int row = b * S_ + q0 + w * 32 + qf * 16 + lhi * 4 + r;
        int col = h * DK_ + df * 16 + l15;
        Og[(size_t)row * D_ + col] = (bf16)(oacc[qf][df][r] * inv);
      }
    }
  }
}

// ---------------------------------------------------------------- launch
extern "C" void kernel_launch(void* const* d_in, const int* in_sizes, int n_in,
                              void* d_out, int out_size, void* d_ws, size_t ws_size,
                              hipStream_t stream) {
  const float* X   = (const float*)d_in[0];
  const float* Wq  = (const float*)d_in[1];
  const float* Wk  = (const float*)d_in[2];
  const float* Wv  = (const float*)d_in[3];
  const float* Wo  = (const float*)d_in[4];
  const float* rel = (const float*)d_in[5];
  float* out = (float*)d_out;
  char* ws = (char*)d_ws;
  const size_t MB = 1u << 20;
  bf16* Xb    = (bf16*)(ws + 0 * MB);    // 8 MB  (also reused as attn output Ob)
  bf16* Wqkvb = (bf16*)(ws + 8 * MB);    // 6 MB  [3072][1024]
  bf16* Wob   = (bf16*)(ws + 14 * MB);   // 2 MB
  bf16* QKVb  = (bf16*)(ws + 16 * MB);   // 24 MB [4096][3072]
  bf16* VTb   = (bf16*)(ws + 40 * MB);   // 8 MB  [2048][2048]
  float* biasTab = (float*)(ws + 48 * MB);  // 16*4095*4 B

  cvt_kernel<<<4096, 256, 0, stream>>>(X,  Xb, NROWS * D_ / 4);
  cvt_kernel<<<1024, 256, 0, stream>>>(Wq, Wqkvb,               D_ * D_ / 4);
  cvt_kernel<<<1024, 256, 0, stream>>>(Wk, Wqkvb + 1024 * 1024, D_ * D_ / 4);
  cvt_kernel<<<1024, 256, 0, stream>>>(Wv, Wqkvb + 2048 * 1024, D_ * D_ / 4);
  cvt_kernel<<<1024, 256, 0, stream>>>(Wo, Wob, D_ * D_ / 4);
  bias_kernel<<<256, 256, 0, stream>>>(rel, biasTab);

  // fused QKV projection: [4096][1024] x [3072][1024]^T -> [4096][3072]
  gemm_bt<1><<<dim3(24, 64), 256, 0, stream>>>(Xb, Wqkvb, QKVb,
      NROWS, 3 * D_, D_, /*colThr=*/1024, /*aQ=*/0.125f, /*a1=*/1.0f);

  transpose_v<<<dim3(16, 8, 2), 256, 0, stream>>>(QKVb, VTb);

  attn_fwd<<<512, 256, 0, stream>>>(QKVb, VTb, biasTab, Xb /*Ob*/);

  gemm_bt<0><<<dim3(8, 64), 256, 0, stream>>>(Xb, Wob, out,
      NROWS, D_, D_, /*colThr=*/0, 1.0f, 1.0f);
}